// Round 3
// baseline (9832.117 us; speedup 1.0000x reference)
//
#include <hip/hip_runtime.h>
#include <hip/hip_bf16.h>

#define TT 512
#define BB 128
#define HH 512
#define ALPHA 0.1f
#define NOISE_S 0.02f

typedef __attribute__((ext_vector_type(8))) short short8;
typedef __attribute__((ext_vector_type(8))) _Float16 half8;
typedef __attribute__((ext_vector_type(4))) float f32x4;

__device__ __forceinline__ unsigned short f2h(float f) {
  return __builtin_bit_cast(unsigned short, (_Float16)f);  // RNE
}

__device__ __forceinline__ float fast_tanh(float x) {
  // tanh(x) = 1 - 2/(exp(2x)+1), exp via v_exp_f32 (2^y), rcp via v_rcp_f32
  float e = __builtin_amdgcn_exp2f(x * 2.8853900817779268f);
  return 1.0f - 2.0f * __builtin_amdgcn_rcpf(e + 1.0f);
}

__device__ __forceinline__ f32x4 mfma16(short8 a, short8 b, f32x4 c) {
  return __builtin_amdgcn_mfma_f32_16x16x32_f16(
      __builtin_bit_cast(half8, a), __builtin_bit_cast(half8, b), c, 0, 0, 0);
}

// ---------------------------------------------------------------------------
// Pack weights (fp32 [H,H] row-major, k=row, n=col) into fp16 MFMA B-fragment
// order. One 16-byte chunk per (kt, nt, lane): element i holds
// W[kt*32 + (lane>>4)*8 + i][nt*16 + (lane&15)].
// Layout in ws:  WA = [wrec11; wrec12] (K=1024,N=512)  chunks [0, 65536)
//                WB = [wrec21; wrec22] (K=1024,N=512)  chunks [65536, 131072)
//                WO = wo padded to N=16 (K=512)        chunks [131072, 132096)
// ---------------------------------------------------------------------------
__global__ void pack_weights(const float* __restrict__ w11, const float* __restrict__ w12,
                             const float* __restrict__ w21, const float* __restrict__ w22,
                             const float* __restrict__ wo, unsigned short* __restrict__ dst) {
  int idx = blockIdx.x * 256 + threadIdx.x;
  if (idx < 131072) {
    int which = idx >> 16;                 // 0: WA, 1: WB
    int c0 = idx & 65535;
    int kt = c0 >> 11, rem = c0 & 2047;
    int nt = rem >> 6, lane = rem & 63;
    const float* wlo = which ? w21 : w11;  // k < 512  (multiplies tanh(h1))
    const float* whi = which ? w22 : w12;  // k >= 512 (multiplies tanh(h2))
    unsigned short* p = dst + (size_t)idx * 8;
    int n = nt * 16 + (lane & 15);
    int kb = kt * 32 + ((lane >> 4) & 3) * 8;
#pragma unroll
    for (int i = 0; i < 8; ++i) {
      int k = kb + i;
      float v = (k < HH) ? wlo[k * HH + n] : whi[(k - HH) * HH + n];
      p[i] = f2h(v);
    }
  } else if (idx < 132096) {
    int c0 = idx - 131072;                 // 0..1023
    int kt = c0 >> 6, lane = c0 & 63;
    unsigned short* p = dst + (size_t)131072 * 8 + (size_t)c0 * 8;
    int n = lane & 15;
    int kb = kt * 32 + ((lane >> 4) & 3) * 8;
#pragma unroll
    for (int i = 0; i < 8; ++i) {
      float v = (n < 3) ? wo[(kb + i) * 3 + n] : 0.0f;
      p[i] = f2h(v);
    }
  }
}

// ---------------------------------------------------------------------------
// Main persistent RNN kernel. 8 blocks x 512 threads; block owns 16 batch
// rows, runs all T=512 steps. h1/h2 fp32 in registers (D-fragment layout);
// tanh(h) packed fp16 in LDS in A-fragment order:
//   tanhA[(k>>3)*128 + row*8 + (k&7)]   (ushort units; k in [0,1024))
//   k in [0,512) = tanh(h1), k in [512,1024) = tanh(h2).
// ---------------------------------------------------------------------------
__global__ __launch_bounds__(512)
void rnn_main(const float* __restrict__ x, const float* __restrict__ wi_stim,
              const float* __restrict__ wi_ctx, const float* __restrict__ noise1,
              const float* __restrict__ noise2, const unsigned short* __restrict__ wpack,
              float* __restrict__ out) {
  __shared__ __align__(16) unsigned short tanhA[32 * 512];  // 32 KB
  __shared__ float xstage[2][16][5];

  const int tid  = threadIdx.x;
  const int w    = tid >> 6;       // wave 0..7, owns j-tiles nt = 4w..4w+3
  const int lane = tid & 63;
  const int c16  = lane & 15;      // A row-select / B col-select / D col
  const int kh   = lane >> 4;      // 0..3, k-group / D row-group
  const int b0   = blockIdx.x * 16;

  const short8* __restrict__ WA = (const short8*)wpack;
  const short8* __restrict__ WB = (const short8*)wpack + 65536;
  const short8* __restrict__ WO = (const short8*)wpack + 131072;

  for (int i = tid; i < 32 * 512; i += 512) tanhA[i] = 0;   // tanh(0) = 0
  if (tid < 80) {
    int b = tid / 5, c = tid % 5;
    xstage[0][b][c] = x[((size_t)(b0 + b) * TT + 0) * 5 + c];
  }

  // per-lane input-weight preload: j = (w*4+q)*16 + c16
  float wis[4][3], wic[4][2];
#pragma unroll
  for (int q = 0; q < 4; ++q) {
    int j = (w * 4 + q) * 16 + c16;
#pragma unroll
    for (int c = 0; c < 3; ++c) wis[q][c] = wi_stim[c * HH + j];
#pragma unroll
    for (int c = 0; c < 2; ++c) wic[q][c] = wi_ctx[c * HH + j];
  }

  float h1[4][4], h2[4][4];   // [q][r]: j = (w*4+q)*16+c16, b = kh*4+r
#pragma unroll
  for (int q = 0; q < 4; ++q)
#pragma unroll
    for (int r = 0; r < 4; ++r) { h1[q][r] = 0.0f; h2[q][r] = 0.0f; }

  const int aoff  = (kh * 16 + c16) * 8;  // lane's A-frag offset within one kt
  const int jbase = w * 64 + c16;

  __syncthreads();

  for (int t = 0; t < TT; ++t) {
    const int buf = t & 1;

    // ---------------- R1: issue noise1 loads, then phase-A MFMA ----------------
    float n1v[4][4];
#pragma unroll
    for (int q = 0; q < 4; ++q) {
      int j = jbase + q * 16;
#pragma unroll
      for (int r = 0; r < 4; ++r)
        n1v[q][r] = noise1[((size_t)t * BB + b0 + kh * 4 + r) * HH + j];
    }
    f32x4 acc0 = {0,0,0,0}, acc1 = {0,0,0,0}, acc2 = {0,0,0,0}, acc3 = {0,0,0,0};
    {
      const short8* WAw = WA + (size_t)(w * 4) * 64 + lane;
#pragma unroll 4
      for (int kt = 0; kt < 32; ++kt) {
        short8 af  = *(const short8*)&tanhA[kt * 512 + aoff];
        short8 wa0 = WAw[kt * 2048 + 0 * 64];
        short8 wa1 = WAw[kt * 2048 + 1 * 64];
        short8 wa2 = WAw[kt * 2048 + 2 * 64];
        short8 wa3 = WAw[kt * 2048 + 3 * 64];
        acc0 = mfma16(af, wa0, acc0);
        acc1 = mfma16(af, wa1, acc1);
        acc2 = mfma16(af, wa2, acc2);
        acc3 = mfma16(af, wa3, acc3);
      }
    }
    __syncthreads();

    // ---------------- R2: h1 update + pack tanh(h1) into kt 0..15 ----------------
#pragma unroll
    for (int q = 0; q < 4; ++q) {
      f32x4 a = q == 0 ? acc0 : q == 1 ? acc1 : q == 2 ? acc2 : acc3;
      int j = jbase + q * 16;
#pragma unroll
      for (int r = 0; r < 4; ++r) {
        int b = kh * 4 + r;
        float pre = a[r] + wis[q][0] * xstage[buf][b][0]
                         + wis[q][1] * xstage[buf][b][1]
                         + wis[q][2] * xstage[buf][b][2]
                         + NOISE_S * n1v[q][r];
        float h = (1.0f - ALPHA) * h1[q][r] + ALPHA * pre;
        h1[q][r] = h;
        tanhA[(j >> 3) * 128 + b * 8 + (j & 7)] = f2h(fast_tanh(h));
      }
    }
    __syncthreads();

    // ---------------- R3: issue noise2 loads, then phase-B MFMA ----------------
    float n2v[4][4];
#pragma unroll
    for (int q = 0; q < 4; ++q) {
      int j = jbase + q * 16;
#pragma unroll
      for (int r = 0; r < 4; ++r)
        n2v[q][r] = noise2[((size_t)t * BB + b0 + kh * 4 + r) * HH + j];
    }
    acc0 = (f32x4){0,0,0,0}; acc1 = (f32x4){0,0,0,0};
    acc2 = (f32x4){0,0,0,0}; acc3 = (f32x4){0,0,0,0};
    {
      const short8* WBw = WB + (size_t)(w * 4) * 64 + lane;
#pragma unroll 4
      for (int kt = 0; kt < 32; ++kt) {
        short8 af  = *(const short8*)&tanhA[kt * 512 + aoff];
        short8 wb0 = WBw[kt * 2048 + 0 * 64];
        short8 wb1 = WBw[kt * 2048 + 1 * 64];
        short8 wb2 = WBw[kt * 2048 + 2 * 64];
        short8 wb3 = WBw[kt * 2048 + 3 * 64];
        acc0 = mfma16(af, wb0, acc0);
        acc1 = mfma16(af, wb1, acc1);
        acc2 = mfma16(af, wb2, acc2);
        acc3 = mfma16(af, wb3, acc3);
      }
    }
    __syncthreads();

    // -------- R4: h2 update + pack tanh(h2) into kt 16..31 + stage x(t+1) --------
    if (t + 1 < TT && tid < 80) {
      int b = tid / 5, c = tid % 5;
      xstage[buf ^ 1][b][c] = x[((size_t)(b0 + b) * TT + (t + 1)) * 5 + c];
    }
#pragma unroll
    for (int q = 0; q < 4; ++q) {
      f32x4 a = q == 0 ? acc0 : q == 1 ? acc1 : q == 2 ? acc2 : acc3;
      int j = jbase + q * 16;
#pragma unroll
      for (int r = 0; r < 4; ++r) {
        int b = kh * 4 + r;
        float pre = a[r] + wic[q][0] * xstage[buf][b][3]
                         + wic[q][1] * xstage[buf][b][4]
                         + NOISE_S * n2v[q][r];
        float h = (1.0f - ALPHA) * h2[q][r] + ALPHA * pre;
        h2[q][r] = h;
        tanhA[(64 + (j >> 3)) * 128 + b * 8 + (j & 7)] = f2h(fast_tanh(h));
      }
    }
    __syncthreads();

    // ---------------- R5: output matvec (wave 0 only, no barrier) ----------------
    // reads tanh(h2_new) = kt 16..31; next step's first write there is R4,
    // three barriers away — safe.
    if (w == 0) {
      f32x4 ao = {0,0,0,0};
#pragma unroll 4
      for (int kt = 0; kt < 16; ++kt) {
        short8 af = *(const short8*)&tanhA[(16 + kt) * 512 + aoff];
        short8 bo = WO[kt * 64 + lane];
        ao = mfma16(af, bo, ao);
      }
      if (c16 < 3) {
#pragma unroll
        for (int r = 0; r < 4; ++r)
          out[((size_t)(b0 + kh * 4 + r) * TT + t) * 3 + c16] = ao[r];
      }
    }
  }
}

extern "C" void kernel_launch(void* const* d_in, const int* in_sizes, int n_in,
                              void* d_out, int out_size, void* d_ws, size_t ws_size,
                              hipStream_t stream) {
  const float* x       = (const float*)d_in[0];
  const float* wi_stim = (const float*)d_in[1];
  const float* w11     = (const float*)d_in[2];
  const float* wi_ctx  = (const float*)d_in[3];
  const float* w22     = (const float*)d_in[4];
  const float* w12     = (const float*)d_in[5];
  const float* w21     = (const float*)d_in[6];
  const float* wo      = (const float*)d_in[7];
  const float* n1      = (const float*)d_in[8];
  const float* n2      = (const float*)d_in[9];
  unsigned short* wpack = (unsigned short*)d_ws;   // needs ~2.02 MB

  pack_weights<<<516, 256, 0, stream>>>(w11, w12, w21, w22, wo, wpack);
  rnn_main<<<8, 512, 0, stream>>>(x, wi_stim, wi_ctx, n1, n2, wpack, (float*)d_out);
}